// Round 2
// baseline (929.659 us; speedup 1.0000x reference)
//
#include <hip/hip_runtime.h>
#include <hip/hip_bf16.h>

#define N_NODES 20000
#define N_EDGES 320000
#define TOT_E   (N_EDGES + N_NODES)   // 340000 with self loops
#define IN_CH   128
#define HEADS   8
#define CH      33
#define DD      264                   // HEADS*CH
#define OUTW    132
#define NEG     0.2f

// ---------------- CSR build ----------------

__global__ void deg_k(const int* __restrict__ ei, int* __restrict__ deg) {
    int e = blockIdx.x * 256 + threadIdx.x;
    if (e >= TOT_E) return;
    int dst = (e < N_EDGES) ? ei[N_EDGES + e] : (e - N_EDGES);
    atomicAdd(&deg[dst], 1);
}

__global__ __launch_bounds__(1024) void scan_k(const int* __restrict__ deg,
                                               int* __restrict__ rowp) {
    __shared__ int part[1024];
    const int PER = 20;  // 1024*20 = 20480 >= 20000
    int t = threadIdx.x;
    int base = t * PER;
    int s = 0;
    for (int i = 0; i < PER; ++i) {
        int idx = base + i;
        if (idx < N_NODES) s += deg[idx];
    }
    part[t] = s;
    __syncthreads();
    for (int off = 1; off < 1024; off <<= 1) {
        int v = 0;
        if (t >= off) v = part[t - off];
        __syncthreads();
        part[t] += v;
        __syncthreads();
    }
    int run = part[t] - s;  // exclusive prefix
    for (int i = 0; i < PER; ++i) {
        int idx = base + i;
        if (idx < N_NODES) { rowp[idx] = run; run += deg[idx]; }
    }
    if (t == 1023) rowp[N_NODES] = part[1023];
}

__global__ void fill_k(const int* __restrict__ ei, const int* __restrict__ rowp,
                       int* __restrict__ cur, int* __restrict__ csr) {
    int e = blockIdx.x * 256 + threadIdx.x;
    if (e >= TOT_E) return;
    int src, dst;
    if (e < N_EDGES) { src = ei[e]; dst = ei[N_EDGES + e]; }
    else             { src = dst = e - N_EDGES; }
    int p = atomicAdd(&cur[dst], 1);
    csr[rowp[dst] + p] = src;
}

// ---------------- GEMM (all fp32): C[M,NC] = A[M,K] @ B[K,NC] (+bias) ----------------

__global__ __launch_bounds__(256) void gemm_k(
    const float* __restrict__ A, int K,
    const float* __restrict__ B, int NC,
    float* __restrict__ C, const float* __restrict__ bias) {
    const int M = N_NODES;
    __shared__ float As[16][65];  // [k][m], padded
    __shared__ float Bs[16][65];  // [k][n]
    int tid = threadIdx.x;
    int m0 = blockIdx.x * 64, n0 = blockIdx.y * 64;
    int tx = tid & 15, ty = tid >> 4;
    float acc[4][4] = {};
    int nk = (K + 15) / 16;
    for (int kb = 0; kb < nk; ++kb) {
        int k0 = kb * 16;
#pragma unroll
        for (int i = 0; i < 4; ++i) {
            int l = tid + 256 * i;
            // A: m = l/16, k = l%16
            int mm = l >> 4, kk = l & 15;
            int gm = m0 + mm, gk = k0 + kk;
            float v = 0.f;
            if (gm < M && gk < K) v = A[(size_t)gm * K + gk];
            As[kk][mm] = v;
            // B: k = l/64, n = l%64
            int bk = l >> 6, bn = l & 63;
            int gk2 = k0 + bk, gn = n0 + bn;
            float bv = 0.f;
            if (gk2 < K && gn < NC) bv = B[(size_t)gk2 * NC + gn];
            Bs[bk][bn] = bv;
        }
        __syncthreads();
#pragma unroll
        for (int kk = 0; kk < 16; ++kk) {
            float a[4], b[4];
#pragma unroll
            for (int i = 0; i < 4; ++i) a[i] = As[kk][ty * 4 + i];
#pragma unroll
            for (int j = 0; j < 4; ++j) b[j] = Bs[kk][tx * 4 + j];
#pragma unroll
            for (int i = 0; i < 4; ++i)
#pragma unroll
                for (int j = 0; j < 4; ++j) acc[i][j] += a[i] * b[j];
        }
        __syncthreads();
    }
#pragma unroll
    for (int i = 0; i < 4; ++i) {
        int gm = m0 + ty * 4 + i;
        if (gm >= M) continue;
#pragma unroll
        for (int j = 0; j < 4; ++j) {
            int gn = n0 + tx * 4 + j;
            if (gn >= NC) continue;
            float v = acc[i][j];
            if (bias) v += bias[gn];
            C[(size_t)gm * NC + gn] = v;
        }
    }
}

// ---------------- attention logits: alpha_s/alpha_d per (node, head) ----------------

__global__ void alpha_k(const float* __restrict__ xh,
                        const float* __restrict__ a_s, const float* __restrict__ a_d,
                        float* __restrict__ as_, float* __restrict__ ad_) {
    int t = blockIdx.x * 256 + threadIdx.x;
    if (t >= N_NODES * HEADS) return;
    int n = t >> 3, h = t & 7;
    const float* row = xh + (size_t)n * DD + h * CH;
    float ss = 0.f, sd = 0.f;
#pragma unroll
    for (int i = 0; i < CH; ++i) {
        float v = row[i];
        ss += v * a_s[h * CH + i];
        sd += v * a_d[h * CH + i];
    }
    as_[t] = ss;
    ad_[t] = sd;
}

// ---------------- per-dst aggregation: softmax over incoming edges + weighted sum ----------------
// one wave (64 threads) per destination node; no float atomics anywhere.

__global__ __launch_bounds__(64) void agg_k(
    const float* __restrict__ xh, const float* __restrict__ as_,
    const float* __restrict__ ad_, const int* __restrict__ rowp,
    const int* __restrict__ csr, const float* __restrict__ bias,
    float* __restrict__ hout) {
    int node = blockIdx.x;
    int lane = threadIdx.x;
    int r0 = rowp[node], r1 = rowp[node + 1];
    int dg = r1 - r0;

    float ad[8];
#pragma unroll
    for (int h = 0; h < 8; ++h) ad[h] = ad_[node * 8 + h];

    // pass 1: segment max per head
    float mx[8];
#pragma unroll
    for (int h = 0; h < 8; ++h) mx[h] = -1e30f;
    for (int j = lane; j < dg; j += 64) {
        int s = csr[r0 + j];
        const float* ap = as_ + (size_t)s * 8;
#pragma unroll
        for (int h = 0; h < 8; ++h) {
            float e = ap[h] + ad[h];
            e = e > 0.f ? e : NEG * e;
            mx[h] = fmaxf(mx[h], e);
        }
    }
#pragma unroll
    for (int h = 0; h < 8; ++h)
        for (int off = 32; off; off >>= 1)
            mx[h] = fmaxf(mx[h], __shfl_xor(mx[h], off, 64));

    // pass 2: exp-sum
    float sm[8] = {0.f, 0.f, 0.f, 0.f, 0.f, 0.f, 0.f, 0.f};
    for (int j = lane; j < dg; j += 64) {
        int s = csr[r0 + j];
        const float* ap = as_ + (size_t)s * 8;
#pragma unroll
        for (int h = 0; h < 8; ++h) {
            float e = ap[h] + ad[h];
            e = e > 0.f ? e : NEG * e;
            sm[h] += __expf(e - mx[h]);
        }
    }
#pragma unroll
    for (int h = 0; h < 8; ++h)
        for (int off = 32; off; off >>= 1)
            sm[h] += __shfl_xor(sm[h], off, 64);
    float inv[8];
#pragma unroll
    for (int h = 0; h < 8; ++h) inv[h] = 1.0f / (sm[h] + 1e-16f);

    // pass 3: weighted feature accumulation (chunked, LDS-staged alphas)
    float4 acc0 = {0.f, 0.f, 0.f, 0.f};
    float4 acc1 = {0.f, 0.f, 0.f, 0.f};
    int h0[4], h1[4];
#pragma unroll
    for (int j = 0; j < 4; ++j) {
        h0[j] = (4 * lane + j) / 33;
        h1[j] = (4 * (lane + 64) + j) / 33;  // only used by lanes 0,1 (always head 7)
    }
    __shared__ float lex[64][8];
    __shared__ int lsrc[64];
    for (int base = 0; base < dg; base += 64) {
        int j = base + lane;
        if (j < dg) {
            int s = csr[r0 + j];
            lsrc[lane] = s;
            const float* ap = as_ + (size_t)s * 8;
#pragma unroll
            for (int h = 0; h < 8; ++h) {
                float e = ap[h] + ad[h];
                e = e > 0.f ? e : NEG * e;
                lex[lane][h] = __expf(e - mx[h]) * inv[h];
            }
        }
        __syncthreads();
        int cnt = min(64, dg - base);
        for (int jj = 0; jj < cnt; ++jj) {
            int s = lsrc[jj];
            const float4* row = (const float4*)(xh + (size_t)s * DD);
            float4 v = row[lane];
            acc0.x += lex[jj][h0[0]] * v.x;
            acc0.y += lex[jj][h0[1]] * v.y;
            acc0.z += lex[jj][h0[2]] * v.z;
            acc0.w += lex[jj][h0[3]] * v.w;
            if (lane < 2) {
                float4 w = row[64 + lane];
                acc1.x += lex[jj][h1[0]] * w.x;
                acc1.y += lex[jj][h1[1]] * w.y;
                acc1.z += lex[jj][h1[2]] * w.z;
                acc1.w += lex[jj][h1[3]] * w.w;
            }
        }
        __syncthreads();
    }

    // epilogue: += bias, elu, store fp32 h for next layer
#pragma unroll
    for (int k = 0; k < 2; ++k) {
        int i4 = lane + 64 * k;
        if (i4 < 66) {
            float4 a = (k == 0) ? acc0 : acc1;
            int c = 4 * i4;
            float vals[4] = {a.x, a.y, a.z, a.w};
            float o[4];
#pragma unroll
            for (int j = 0; j < 4; ++j) {
                float v = vals[j] + bias[c + j];
                o[j] = v > 0.f ? v : (__expf(v) - 1.f);
            }
            float4 w = {o[0], o[1], o[2], o[3]};
            *(float4*)(hout + (size_t)node * DD + c) = w;
        }
    }
}

// ---------------- launch ----------------

extern "C" void kernel_launch(void* const* d_in, const int* in_sizes, int n_in,
                              void* d_out, int out_size, void* d_ws, size_t ws_size,
                              hipStream_t stream) {
    const float* x  = (const float*)d_in[0];
    const int*   ei = (const int*)d_in[1];
    const float* W[4]  = {(const float*)d_in[2],  (const float*)d_in[6],
                          (const float*)d_in[10], (const float*)d_in[14]};
    const float* As[4] = {(const float*)d_in[3],  (const float*)d_in[7],
                          (const float*)d_in[11], (const float*)d_in[15]};
    const float* Ad[4] = {(const float*)d_in[4],  (const float*)d_in[8],
                          (const float*)d_in[12], (const float*)d_in[16]};
    const float* Bb[4] = {(const float*)d_in[5],  (const float*)d_in[9],
                          (const float*)d_in[13], (const float*)d_in[17]};
    const float* Wh = (const float*)d_in[18];
    const float* bh = (const float*)d_in[19];

    // workspace carve (fp32 h ping-pong + logits + CSR)
    float* hA  = (float*)d_ws;                       // [N, 264]
    float* hB  = hA + (size_t)N_NODES * DD;          // [N, 264] (xh)
    float* as_ = hB + (size_t)N_NODES * DD;          // [N, 8]
    float* ad_ = as_ + (size_t)N_NODES * HEADS;      // [N, 8]
    int* deg   = (int*)(ad_ + (size_t)N_NODES * HEADS);
    int* cur   = deg + N_NODES;
    int* rowp  = cur + N_NODES;
    int* csr   = rowp + (N_NODES + 1);

    // CSR build
    hipMemsetAsync(deg, 0, sizeof(int) * 2 * N_NODES, stream);  // deg + cur
    int egrid = (TOT_E + 255) / 256;
    deg_k<<<egrid, 256, 0, stream>>>(ei, deg);
    scan_k<<<1, 1024, 0, stream>>>(deg, rowp);
    fill_k<<<egrid, 256, 0, stream>>>(ei, rowp, cur, csr);

    dim3 gD((N_NODES + 63) / 64, (DD + 63) / 64);    // 313 x 5
    dim3 gH((N_NODES + 63) / 64, (OUTW + 63) / 64);  // 313 x 3
    int agrid = (N_NODES * HEADS + 255) / 256;

    // layer 0 (A = x, K=128)
    gemm_k<<<gD, 256, 0, stream>>>(x, IN_CH, W[0], DD, hB, nullptr);
    alpha_k<<<agrid, 256, 0, stream>>>(hB, As[0], Ad[0], as_, ad_);
    agg_k<<<N_NODES, 64, 0, stream>>>(hB, as_, ad_, rowp, csr, Bb[0], hA);

    // layers 1..3 (A = hA, K=264)
    for (int l = 1; l < 4; ++l) {
        gemm_k<<<gD, 256, 0, stream>>>(hA, DD, W[l], DD, hB, nullptr);
        alpha_k<<<agrid, 256, 0, stream>>>(hB, As[l], Ad[l], as_, ad_);
        agg_k<<<N_NODES, 64, 0, stream>>>(hB, as_, ad_, rowp, csr, Bb[l], hA);
    }

    // head readout -> fp32 out
    gemm_k<<<gH, 256, 0, stream>>>(hA, DD, Wh, OUTW, (float*)d_out, bh);
}

// Round 3
// 614.111 us; speedup vs baseline: 1.5138x; 1.5138x over previous
//
#include <hip/hip_runtime.h>
#include <hip/hip_bf16.h>

#define N_NODES 20000
#define N_EDGES 320000
#define TOT_E   (N_EDGES + N_NODES)   // 340000 with self loops
#define IN_CH   128
#define HEADS   8
#define CH      33
#define DD      264                   // HEADS*CH
#define OUTW    132
#define NEG     0.2f

#define LDH     272                   // hB row stride (17 * 16)
#define LDA     288                   // hA (hi/lo bf16) row stride, K padded to 9*32
#define NT_HID  17                    // N tiles (16 wide) for hidden gemms
#define NT_HEAD 9                     // N tiles for head gemm (132 -> 144)

typedef unsigned short ushort;
typedef short bf16x8 __attribute__((ext_vector_type(8)));
typedef float f32x4  __attribute__((ext_vector_type(4)));

__device__ inline void split2(float v, ushort& hi, ushort& lo) {
    __hip_bfloat16 h = __float2bfloat16(v);
    float r = v - __bfloat162float(h);
    __hip_bfloat16 l = __float2bfloat16(r);
    hi = *(ushort*)&h;
    lo = *(ushort*)&l;
}

// ---------------- CSR build ----------------

__global__ void deg_k(const int* __restrict__ ei, int* __restrict__ deg) {
    int e = blockIdx.x * 256 + threadIdx.x;
    if (e >= TOT_E) return;
    int dst = (e < N_EDGES) ? ei[N_EDGES + e] : (e - N_EDGES);
    atomicAdd(&deg[dst], 1);
}

__global__ __launch_bounds__(1024) void scan_k(const int* __restrict__ deg,
                                               int* __restrict__ rowp) {
    __shared__ int part[1024];
    const int PER = 20;
    int t = threadIdx.x;
    int base = t * PER;
    int s = 0;
    for (int i = 0; i < PER; ++i) {
        int idx = base + i;
        if (idx < N_NODES) s += deg[idx];
    }
    part[t] = s;
    __syncthreads();
    for (int off = 1; off < 1024; off <<= 1) {
        int v = 0;
        if (t >= off) v = part[t - off];
        __syncthreads();
        part[t] += v;
        __syncthreads();
    }
    int run = part[t] - s;
    for (int i = 0; i < PER; ++i) {
        int idx = base + i;
        if (idx < N_NODES) { rowp[idx] = run; run += deg[idx]; }
    }
    if (t == 1023) rowp[N_NODES] = part[1023];
}

__global__ void fill_k(const int* __restrict__ ei, const int* __restrict__ rowp,
                       int* __restrict__ cur, int* __restrict__ csr) {
    int e = blockIdx.x * 256 + threadIdx.x;
    if (e >= TOT_E) return;
    int src, dst;
    if (e < N_EDGES) { src = ei[e]; dst = ei[N_EDGES + e]; }
    else             { src = dst = e - N_EDGES; }
    int p = atomicAdd(&cur[dst], 1);
    csr[rowp[dst] + p] = src;
}

// ---------------- input x -> hi/lo bf16 split (into hA, stride LDA) ----------------

__global__ void splitx_k(const float* __restrict__ x,
                         ushort* __restrict__ ahi, ushort* __restrict__ alo) {
    int idx = blockIdx.x * 256 + threadIdx.x;
    if (idx >= N_NODES * IN_CH) return;
    int n = idx >> 7, k = idx & 127;
    ushort hi, lo;
    split2(x[idx], hi, lo);
    ahi[(size_t)n * LDA + k] = hi;
    alo[(size_t)n * LDA + k] = lo;
}

// ---------------- weight -> fragment-ordered hi/lo bf16 ----------------
// Wfrag[((p*NT + t)*64 + kq*16 + m)*8 + j] = W[p*32 + kq*8 + j][t*16 + m]
// (p: k-panel of 32, t: n-tile of 16; chunk kq*16+m matches lane id in MFMA frag)

__global__ void convw_k(const float* __restrict__ W, int K, int NC, int NT,
                        ushort* __restrict__ fhi, ushort* __restrict__ flo,
                        int total) {
    int gid = blockIdx.x * 256 + threadIdx.x;
    if (gid >= total) return;   // total = panels*NT*64
    int p = gid / (NT * 64);
    int rem = gid % (NT * 64);
    int t = rem >> 6, c = rem & 63;
    int kq = c >> 4, m = c & 15;
    int n = t * 16 + m;
    ushort hi8[8], lo8[8];
#pragma unroll
    for (int j = 0; j < 8; ++j) {
        int k = p * 32 + kq * 8 + j;
        float v = (k < K && n < NC) ? W[(size_t)k * NC + n] : 0.f;
        split2(v, hi8[j], lo8[j]);
    }
    size_t o = ((size_t)gid) * 8;
#pragma unroll
    for (int j = 0; j < 8; ++j) { fhi[o + j] = hi8[j]; flo[o + j] = lo8[j]; }
}

// ---------------- MFMA GEMM: C[M, NC] = A[M, K] @ B[K, NC] ----------------
// A: hi/lo bf16, row stride lda. B: fragment-ordered hi/lo. 3-term split product.
// block: 256 thr = 4 waves; block tile 64(M) x 9 n-tiles (blockIdx.y selects tile group)

__global__ __launch_bounds__(256) void gemm_mfma(
    const ushort* __restrict__ Ahi, const ushort* __restrict__ Alo, int lda, int kpanels,
    const ushort* __restrict__ Bhi, const ushort* __restrict__ Blo, int NTtot,
    float* __restrict__ C, int ldc, int ncguard, const float* __restrict__ bias) {
    __shared__ ushort Al[2][4][512];   // [hi/lo][wave m-tile][chunk*8]
    __shared__ ushort Bl[2][9][512];   // [hi/lo][n-tile][chunk*8]
    int tid = threadIdx.x;
    int m0 = blockIdx.x * 64;
    int t0 = blockIdx.y * 9;
    int nt = NTtot - t0; if (nt > 9) nt = 9;

    f32x4 acc[9];
#pragma unroll
    for (int t = 0; t < 9; ++t) acc[t] = (f32x4){0.f, 0.f, 0.f, 0.f};

    int w = tid >> 6, lane = tid & 63;

    for (int p = 0; p < kpanels; ++p) {
        // stage A: 512 chunk-copies of 16 B (hi then lo)
#pragma unroll
        for (int i = 0; i < 2; ++i) {
            int id = tid + 256 * i;
            int hl = id >> 8;          // 0 = hi, 1 = lo
            int cid = id & 255;
            int mrow = cid >> 2, kq = cid & 3;
            int gm = m0 + mrow;
            uint4 v = {0, 0, 0, 0};
            if (gm < N_NODES) {
                const ushort* src = (hl ? Alo : Ahi) + (size_t)gm * lda + p * 32 + kq * 8;
                v = *(const uint4*)src;
            }
            *(uint4*)&Al[hl][mrow >> 4][(kq * 16 + (mrow & 15)) * 8] = v;
        }
        // stage B: nt*128 chunk-copies of 16 B
        int nb = nt * 64;
        for (int id = tid; id < 2 * nb; id += 256) {
            int hl = id >= nb;
            int c2 = id - hl * nb;
            int t = c2 >> 6, c = c2 & 63;
            const ushort* src = (hl ? Blo : Bhi) + ((size_t)(p * NTtot + t0 + t) * 64 + c) * 8;
            *(uint4*)&Bl[hl][t][c * 8] = *(const uint4*)src;
        }
        __syncthreads();

        bf16x8 ahi = *(const bf16x8*)&Al[0][w][lane * 8];
        bf16x8 alo = *(const bf16x8*)&Al[1][w][lane * 8];
#pragma unroll
        for (int t = 0; t < 9; ++t) {
            if (t < nt) {
                bf16x8 bh = *(const bf16x8*)&Bl[0][t][lane * 8];
                bf16x8 bl = *(const bf16x8*)&Bl[1][t][lane * 8];
                acc[t] = __builtin_amdgcn_mfma_f32_16x16x32_bf16(ahi, bh, acc[t], 0, 0, 0);
                acc[t] = __builtin_amdgcn_mfma_f32_16x16x32_bf16(ahi, bl, acc[t], 0, 0, 0);
                acc[t] = __builtin_amdgcn_mfma_f32_16x16x32_bf16(alo, bh, acc[t], 0, 0, 0);
            }
        }
        __syncthreads();
    }

    // store: C/D layout col = lane&15, row = (lane>>4)*4 + r
    int rbase = m0 + w * 16 + ((lane >> 4) << 2);
    int cbase = t0 * 16 + (lane & 15);
#pragma unroll
    for (int t = 0; t < 9; ++t) {
        if (t < nt) {
            int gn = cbase + t * 16;
            if (gn >= ncguard) continue;
            float b = bias ? bias[gn] : 0.f;
#pragma unroll
            for (int r = 0; r < 4; ++r) {
                int gm = rbase + r;
                if (gm < N_NODES) C[(size_t)gm * ldc + gn] = acc[t][r] + b;
            }
        }
    }
}

// ---------------- attention logits per (node, head) ----------------

__global__ void alpha_k(const float* __restrict__ xh,
                        const float* __restrict__ a_s, const float* __restrict__ a_d,
                        float* __restrict__ as_, float* __restrict__ ad_) {
    int t = blockIdx.x * 256 + threadIdx.x;
    if (t >= N_NODES * HEADS) return;
    int n = t >> 3, h = t & 7;
    const float* row = xh + (size_t)n * LDH + h * CH;
    float ss = 0.f, sd = 0.f;
#pragma unroll
    for (int i = 0; i < CH; ++i) {
        float v = row[i];
        ss += v * a_s[h * CH + i];
        sd += v * a_d[h * CH + i];
    }
    as_[t] = ss;
    ad_[t] = sd;
}

// ---------------- per-dst softmax aggregation; writes next-layer A as hi/lo bf16 ----------------

__global__ __launch_bounds__(64) void agg_k(
    const float* __restrict__ xh, const float* __restrict__ as_,
    const float* __restrict__ ad_, const int* __restrict__ rowp,
    const int* __restrict__ csr, const float* __restrict__ bias,
    ushort* __restrict__ outhi, ushort* __restrict__ outlo) {
    int node = blockIdx.x;
    int lane = threadIdx.x;
    int r0 = rowp[node], r1 = rowp[node + 1];
    int dg = r1 - r0;

    float ad[8];
#pragma unroll
    for (int h = 0; h < 8; ++h) ad[h] = ad_[node * 8 + h];

    float mx[8];
#pragma unroll
    for (int h = 0; h < 8; ++h) mx[h] = -1e30f;
    for (int j = lane; j < dg; j += 64) {
        int s = csr[r0 + j];
        const float* ap = as_ + (size_t)s * 8;
#pragma unroll
        for (int h = 0; h < 8; ++h) {
            float e = ap[h] + ad[h];
            e = e > 0.f ? e : NEG * e;
            mx[h] = fmaxf(mx[h], e);
        }
    }
#pragma unroll
    for (int h = 0; h < 8; ++h)
        for (int off = 32; off; off >>= 1)
            mx[h] = fmaxf(mx[h], __shfl_xor(mx[h], off, 64));

    float sm[8] = {0.f, 0.f, 0.f, 0.f, 0.f, 0.f, 0.f, 0.f};
    for (int j = lane; j < dg; j += 64) {
        int s = csr[r0 + j];
        const float* ap = as_ + (size_t)s * 8;
#pragma unroll
        for (int h = 0; h < 8; ++h) {
            float e = ap[h] + ad[h];
            e = e > 0.f ? e : NEG * e;
            sm[h] += __expf(e - mx[h]);
        }
    }
#pragma unroll
    for (int h = 0; h < 8; ++h)
        for (int off = 32; off; off >>= 1)
            sm[h] += __shfl_xor(sm[h], off, 64);
    float inv[8];
#pragma unroll
    for (int h = 0; h < 8; ++h) inv[h] = 1.0f / (sm[h] + 1e-16f);

    float4 acc0 = {0.f, 0.f, 0.f, 0.f};
    float4 acc1 = {0.f, 0.f, 0.f, 0.f};
    int h0[4], h1[4];
#pragma unroll
    for (int j = 0; j < 4; ++j) {
        h0[j] = (4 * lane + j) / 33;
        h1[j] = (4 * (lane + 64) + j) / 33;
    }
    __shared__ float lex[64][8];
    __shared__ int lsrc[64];
    for (int base = 0; base < dg; base += 64) {
        int j = base + lane;
        if (j < dg) {
            int s = csr[r0 + j];
            lsrc[lane] = s;
            const float* ap = as_ + (size_t)s * 8;
#pragma unroll
            for (int h = 0; h < 8; ++h) {
                float e = ap[h] + ad[h];
                e = e > 0.f ? e : NEG * e;
                lex[lane][h] = __expf(e - mx[h]) * inv[h];
            }
        }
        __syncthreads();
        int cnt = min(64, dg - base);
        for (int jj = 0; jj < cnt; ++jj) {
            int s = lsrc[jj];
            const float4* row = (const float4*)(xh + (size_t)s * LDH);
            float4 v = row[lane];
            acc0.x += lex[jj][h0[0]] * v.x;
            acc0.y += lex[jj][h0[1]] * v.y;
            acc0.z += lex[jj][h0[2]] * v.z;
            acc0.w += lex[jj][h0[3]] * v.w;
            if (lane < 2) {
                float4 w2 = row[64 + lane];
                acc1.x += lex[jj][h1[0]] * w2.x;
                acc1.y += lex[jj][h1[1]] * w2.y;
                acc1.z += lex[jj][h1[2]] * w2.z;
                acc1.w += lex[jj][h1[3]] * w2.w;
            }
        }
        __syncthreads();
    }

    // epilogue: bias + elu, split to hi/lo bf16 (next gemm A operand), zero K-pad
#pragma unroll
    for (int k = 0; k < 2; ++k) {
        int i4 = lane + 64 * k;
        if (i4 < 66) {
            float4 a = (k == 0) ? acc0 : acc1;
            float vals[4] = {a.x, a.y, a.z, a.w};
            ushort hi4[4], lo4[4];
#pragma unroll
            for (int j = 0; j < 4; ++j) {
                float v = vals[j] + bias[i4 * 4 + j];
                v = v > 0.f ? v : (__expf(v) - 1.f);
                split2(v, hi4[j], lo4[j]);
            }
            size_t o = (size_t)node * LDA + i4 * 4;
            *(ushort4*)(outhi + o) = *(ushort4*)hi4;
            *(ushort4*)(outlo + o) = *(ushort4*)lo4;
        } else if (i4 < 72) {
            ushort4 z = {0, 0, 0, 0};
            size_t o = (size_t)node * LDA + i4 * 4;
            *(ushort4*)(outhi + o) = z;
            *(ushort4*)(outlo + o) = z;
        }
    }
}

// ---------------- launch ----------------

extern "C" void kernel_launch(void* const* d_in, const int* in_sizes, int n_in,
                              void* d_out, int out_size, void* d_ws, size_t ws_size,
                              hipStream_t stream) {
    const float* x  = (const float*)d_in[0];
    const int*   ei = (const int*)d_in[1];
    const float* W[4]  = {(const float*)d_in[2],  (const float*)d_in[6],
                          (const float*)d_in[10], (const float*)d_in[14]};
    const float* As[4] = {(const float*)d_in[3],  (const float*)d_in[7],
                          (const float*)d_in[11], (const float*)d_in[15]};
    const float* Ad[4] = {(const float*)d_in[4],  (const float*)d_in[8],
                          (const float*)d_in[12], (const float*)d_in[16]};
    const float* Bb[4] = {(const float*)d_in[5],  (const float*)d_in[9],
                          (const float*)d_in[13], (const float*)d_in[17]};
    const float* Wh = (const float*)d_in[18];
    const float* bh = (const float*)d_in[19];

    // ---- workspace carve ----
    char* p = (char*)d_ws;
    float* hB   = (float*)p;            p += (size_t)N_NODES * LDH * 4;      // xh fp32
    ushort* hAhi = (ushort*)p;          p += (size_t)N_NODES * LDA * 2;      // A hi
    ushort* hAlo = (ushort*)p;          p += (size_t)N_NODES * LDA * 2;      // A lo
    float* as_  = (float*)p;            p += (size_t)N_NODES * HEADS * 4;
    float* ad_  = (float*)p;            p += (size_t)N_NODES * HEADS * 4;
    // weight fragments
    const int wsz0 = 4 * NT_HID * 512;   // W0: 4 panels
    const int wszH = 9 * NT_HID * 512;   // W1-3: 9 panels
    const int wszO = 9 * NT_HEAD * 512;  // head
    ushort* wfhi[4]; ushort* wflo[4];
    for (int l = 0; l < 4; ++l) {
        int sz = (l == 0) ? wsz0 : wszH;
        wfhi[l] = (ushort*)p; p += (size_t)sz * 2;
        wflo[l] = (ushort*)p; p += (size_t)sz * 2;
    }
    ushort* whhi = (ushort*)p; p += (size_t)wszO * 2;
    ushort* whlo = (ushort*)p; p += (size_t)wszO * 2;
    int* deg  = (int*)p;  p += N_NODES * 4;
    int* cur  = (int*)p;  p += N_NODES * 4;
    int* rowp = (int*)p;  p += (N_NODES + 1) * 4;
    int* csr  = (int*)p;  p += (size_t)TOT_E * 4;

    // ---- CSR build ----
    hipMemsetAsync(deg, 0, sizeof(int) * 2 * N_NODES, stream);  // deg + cur
    int egrid = (TOT_E + 255) / 256;
    deg_k<<<egrid, 256, 0, stream>>>(ei, deg);
    scan_k<<<1, 1024, 0, stream>>>(deg, rowp);
    fill_k<<<egrid, 256, 0, stream>>>(ei, rowp, cur, csr);

    // ---- weight + input conversion ----
    splitx_k<<<(N_NODES * IN_CH + 255) / 256, 256, 0, stream>>>(x, hAhi, hAlo);
    {
        int tot = 4 * NT_HID * 64;
        convw_k<<<(tot + 255) / 256, 256, 0, stream>>>(W[0], IN_CH, DD, NT_HID, wfhi[0], wflo[0], tot);
    }
    for (int l = 1; l < 4; ++l) {
        int tot = 9 * NT_HID * 64;
        convw_k<<<(tot + 255) / 256, 256, 0, stream>>>(W[l], DD, DD, NT_HID, wfhi[l], wflo[l], tot);
    }
    {
        int tot = 9 * NT_HEAD * 64;
        convw_k<<<(tot + 255) / 256, 256, 0, stream>>>(Wh, DD, OUTW, NT_HEAD, whhi, whlo, tot);
    }

    dim3 gG((N_NODES + 63) / 64, 2);   // hidden gemms: 17 tiles = 9 + 8
    dim3 gO((N_NODES + 63) / 64, 1);   // head gemm: 9 tiles
    int agrid = (N_NODES * HEADS + 255) / 256;

    for (int l = 0; l < 4; ++l) {
        int kp = (l == 0) ? 4 : 9;
        gemm_mfma<<<gG, 256, 0, stream>>>(hAhi, hAlo, LDA, kp,
                                          wfhi[l], wflo[l], NT_HID,
                                          hB, LDH, LDH, nullptr);
        alpha_k<<<agrid, 256, 0, stream>>>(hB, As[l], Ad[l], as_, ad_);
        agg_k<<<N_NODES, 64, 0, stream>>>(hB, as_, ad_, rowp, csr, Bb[l], hAhi, hAlo);
    }

    // head readout -> fp32 out [N, 132]
    gemm_mfma<<<gO, 256, 0, stream>>>(hAhi, hAlo, LDA, 9,
                                      whhi, whlo, NT_HEAD,
                                      (float*)d_out, OUTW, OUTW, bh);
}

// Round 4
// 596.345 us; speedup vs baseline: 1.5589x; 1.0298x over previous
//
#include <hip/hip_runtime.h>
#include <hip/hip_bf16.h>

#define N_NODES 20000
#define N_EDGES 320000
#define TOT_E   (N_EDGES + N_NODES)   // 340000 with self loops
#define IN_CH   128
#define HEADS   8
#define CH      33
#define DD      264                   // HEADS*CH
#define OUTW    132
#define NEG     0.2f

#define LDH     272                   // hB row stride (17 * 16)
#define LDB     272                   // bf16 payload row stride
#define LDA     288                   // hA (hi/lo bf16) row stride, K padded to 9*32
#define NT_HID  17                    // N tiles (16 wide) for hidden gemms
#define NT_HEAD 9                     // N tiles for head gemm (132 -> 144)

typedef unsigned short ushort;
typedef short bf16x8 __attribute__((ext_vector_type(8)));
typedef float f32x4  __attribute__((ext_vector_type(4)));

__device__ inline void split2(float v, ushort& hi, ushort& lo) {
    __hip_bfloat16 h = __float2bfloat16(v);
    float r = v - __bfloat162float(h);
    __hip_bfloat16 l = __float2bfloat16(r);
    hi = *(ushort*)&h;
    lo = *(ushort*)&l;
}

__device__ inline float bf2f(ushort u) {
    union { unsigned int i; float f; } c;
    c.i = ((unsigned int)u) << 16;
    return c.f;
}

// ---------------- CSR build ----------------

__global__ void deg_k(const int* __restrict__ ei, int* __restrict__ deg) {
    int e = blockIdx.x * 256 + threadIdx.x;
    if (e >= TOT_E) return;
    int dst = (e < N_EDGES) ? ei[N_EDGES + e] : (e - N_EDGES);
    atomicAdd(&deg[dst], 1);
}

__global__ __launch_bounds__(1024) void scan_k(const int* __restrict__ deg,
                                               int* __restrict__ rowp) {
    __shared__ int part[1024];
    const int PER = 20;
    int t = threadIdx.x;
    int base = t * PER;
    int s = 0;
    for (int i = 0; i < PER; ++i) {
        int idx = base + i;
        if (idx < N_NODES) s += deg[idx];
    }
    part[t] = s;
    __syncthreads();
    for (int off = 1; off < 1024; off <<= 1) {
        int v = 0;
        if (t >= off) v = part[t - off];
        __syncthreads();
        part[t] += v;
        __syncthreads();
    }
    int run = part[t] - s;
    for (int i = 0; i < PER; ++i) {
        int idx = base + i;
        if (idx < N_NODES) { rowp[idx] = run; run += deg[idx]; }
    }
    if (t == 1023) rowp[N_NODES] = part[1023];
}

__global__ void fill_k(const int* __restrict__ ei, const int* __restrict__ rowp,
                       int* __restrict__ cur, int* __restrict__ csr) {
    int e = blockIdx.x * 256 + threadIdx.x;
    if (e >= TOT_E) return;
    int src, dst;
    if (e < N_EDGES) { src = ei[e]; dst = ei[N_EDGES + e]; }
    else             { src = dst = e - N_EDGES; }
    int p = atomicAdd(&cur[dst], 1);
    csr[rowp[dst] + p] = src;
}

// ---------------- input x -> hi/lo bf16 split (into hA, stride LDA) ----------------

__global__ void splitx_k(const float* __restrict__ x,
                         ushort* __restrict__ ahi, ushort* __restrict__ alo) {
    int idx = blockIdx.x * 256 + threadIdx.x;
    if (idx >= N_NODES * IN_CH) return;
    int n = idx >> 7, k = idx & 127;
    ushort hi, lo;
    split2(x[idx], hi, lo);
    ahi[(size_t)n * LDA + k] = hi;
    alo[(size_t)n * LDA + k] = lo;
}

// ---------------- weight -> fragment-ordered hi/lo bf16 ----------------
// Wfrag[((p*NT + t)*64 + kq*16 + m)*8 + j] = W[p*32 + kq*8 + j][t*16 + m]

__global__ void convw_k(const float* __restrict__ W, int K, int NC, int NT,
                        ushort* __restrict__ fhi, ushort* __restrict__ flo,
                        int total) {
    int gid = blockIdx.x * 256 + threadIdx.x;
    if (gid >= total) return;   // total = panels*NT*64
    int p = gid / (NT * 64);
    int rem = gid % (NT * 64);
    int t = rem >> 6, c = rem & 63;
    int kq = c >> 4, m = c & 15;
    int n = t * 16 + m;
    ushort hi8[8], lo8[8];
#pragma unroll
    for (int j = 0; j < 8; ++j) {
        int k = p * 32 + kq * 8 + j;
        float v = (k < K && n < NC) ? W[(size_t)k * NC + n] : 0.f;
        split2(v, hi8[j], lo8[j]);
    }
    size_t o = ((size_t)gid) * 8;
#pragma unroll
    for (int j = 0; j < 8; ++j) { fhi[o + j] = hi8[j]; flo[o + j] = lo8[j]; }
}

// ---------------- MFMA GEMM: C[M, NC] = A[M, K] @ B[K, NC] ----------------
// A: hi/lo bf16, row stride lda. B: fragment-ordered hi/lo. 3-term split product.
// Optionally also writes a bf16 copy of C (gather payload for agg_k).

__global__ __launch_bounds__(256) void gemm_mfma(
    const ushort* __restrict__ Ahi, const ushort* __restrict__ Alo, int lda, int kpanels,
    const ushort* __restrict__ Bhi, const ushort* __restrict__ Blo, int NTtot,
    float* __restrict__ C, int ldc, int ncguard, const float* __restrict__ bias,
    ushort* __restrict__ Cb16) {
    __shared__ ushort Al[2][4][512];   // [hi/lo][wave m-tile][chunk*8]
    __shared__ ushort Bl[2][9][512];   // [hi/lo][n-tile][chunk*8]
    int tid = threadIdx.x;
    int m0 = blockIdx.x * 64;
    int t0 = blockIdx.y * 9;
    int nt = NTtot - t0; if (nt > 9) nt = 9;

    f32x4 acc[9];
#pragma unroll
    for (int t = 0; t < 9; ++t) acc[t] = (f32x4){0.f, 0.f, 0.f, 0.f};

    int w = tid >> 6, lane = tid & 63;

    for (int p = 0; p < kpanels; ++p) {
#pragma unroll
        for (int i = 0; i < 2; ++i) {
            int id = tid + 256 * i;
            int hl = id >> 8;          // 0 = hi, 1 = lo
            int cid = id & 255;
            int mrow = cid >> 2, kq = cid & 3;
            int gm = m0 + mrow;
            uint4 v = {0, 0, 0, 0};
            if (gm < N_NODES) {
                const ushort* src = (hl ? Alo : Ahi) + (size_t)gm * lda + p * 32 + kq * 8;
                v = *(const uint4*)src;
            }
            *(uint4*)&Al[hl][mrow >> 4][(kq * 16 + (mrow & 15)) * 8] = v;
        }
        int nb = nt * 64;
        for (int id = tid; id < 2 * nb; id += 256) {
            int hl = id >= nb;
            int c2 = id - hl * nb;
            int t = c2 >> 6, c = c2 & 63;
            const ushort* src = (hl ? Blo : Bhi) + ((size_t)(p * NTtot + t0 + t) * 64 + c) * 8;
            *(uint4*)&Bl[hl][t][c * 8] = *(const uint4*)src;
        }
        __syncthreads();

        bf16x8 ahi = *(const bf16x8*)&Al[0][w][lane * 8];
        bf16x8 alo = *(const bf16x8*)&Al[1][w][lane * 8];
#pragma unroll
        for (int t = 0; t < 9; ++t) {
            if (t < nt) {
                bf16x8 bh = *(const bf16x8*)&Bl[0][t][lane * 8];
                bf16x8 bl = *(const bf16x8*)&Bl[1][t][lane * 8];
                acc[t] = __builtin_amdgcn_mfma_f32_16x16x32_bf16(ahi, bh, acc[t], 0, 0, 0);
                acc[t] = __builtin_amdgcn_mfma_f32_16x16x32_bf16(ahi, bl, acc[t], 0, 0, 0);
                acc[t] = __builtin_amdgcn_mfma_f32_16x16x32_bf16(alo, bh, acc[t], 0, 0, 0);
            }
        }
        __syncthreads();
    }

    // store: C/D layout col = lane&15, row = (lane>>4)*4 + r
    int rbase = m0 + w * 16 + ((lane >> 4) << 2);
    int cbase = t0 * 16 + (lane & 15);
#pragma unroll
    for (int t = 0; t < 9; ++t) {
        if (t < nt) {
            int gn = cbase + t * 16;
            if (gn >= ncguard) continue;
            float b = bias ? bias[gn] : 0.f;
#pragma unroll
            for (int r = 0; r < 4; ++r) {
                int gm = rbase + r;
                if (gm < N_NODES) {
                    float v = acc[t][r] + b;
                    C[(size_t)gm * ldc + gn] = v;
                    if (Cb16) {
                        __hip_bfloat16 bv = __float2bfloat16(v);
                        Cb16[(size_t)gm * LDB + gn] = *(ushort*)&bv;
                    }
                }
            }
        }
    }
}

// ---------------- attention logits per (node, head) ----------------

__global__ void alpha_k(const float* __restrict__ xh,
                        const float* __restrict__ a_s, const float* __restrict__ a_d,
                        float* __restrict__ as_, float* __restrict__ ad_) {
    int t = blockIdx.x * 256 + threadIdx.x;
    if (t >= N_NODES * HEADS) return;
    int n = t >> 3, h = t & 7;
    const float* row = xh + (size_t)n * LDH + h * CH;
    float ss = 0.f, sd = 0.f;
#pragma unroll
    for (int i = 0; i < CH; ++i) {
        float v = row[i];
        ss += v * a_s[h * CH + i];
        sd += v * a_d[h * CH + i];
    }
    as_[t] = ss;
    ad_[t] = sd;
}

// ---------------- per-dst softmax aggregation; gathers bf16 payload ----------------

__global__ __launch_bounds__(64) void agg_k(
    const ushort* __restrict__ xb, const float* __restrict__ as_,
    const float* __restrict__ ad_, const int* __restrict__ rowp,
    const int* __restrict__ csr, const float* __restrict__ bias,
    ushort* __restrict__ outhi, ushort* __restrict__ outlo) {
    int node = blockIdx.x;
    int lane = threadIdx.x;
    int r0 = rowp[node], r1 = rowp[node + 1];
    int dg = r1 - r0;

    float ad[8];
#pragma unroll
    for (int h = 0; h < 8; ++h) ad[h] = ad_[node * 8 + h];

    float mx[8];
#pragma unroll
    for (int h = 0; h < 8; ++h) mx[h] = -1e30f;
    for (int j = lane; j < dg; j += 64) {
        int s = csr[r0 + j];
        const float* ap = as_ + (size_t)s * 8;
#pragma unroll
        for (int h = 0; h < 8; ++h) {
            float e = ap[h] + ad[h];
            e = e > 0.f ? e : NEG * e;
            mx[h] = fmaxf(mx[h], e);
        }
    }
#pragma unroll
    for (int h = 0; h < 8; ++h)
        for (int off = 32; off; off >>= 1)
            mx[h] = fmaxf(mx[h], __shfl_xor(mx[h], off, 64));

    float sm[8] = {0.f, 0.f, 0.f, 0.f, 0.f, 0.f, 0.f, 0.f};
    for (int j = lane; j < dg; j += 64) {
        int s = csr[r0 + j];
        const float* ap = as_ + (size_t)s * 8;
#pragma unroll
        for (int h = 0; h < 8; ++h) {
            float e = ap[h] + ad[h];
            e = e > 0.f ? e : NEG * e;
            sm[h] += __expf(e - mx[h]);
        }
    }
#pragma unroll
    for (int h = 0; h < 8; ++h)
        for (int off = 32; off; off >>= 1)
            sm[h] += __shfl_xor(sm[h], off, 64);
    float inv[8];
#pragma unroll
    for (int h = 0; h < 8; ++h) inv[h] = 1.0f / (sm[h] + 1e-16f);

    float4 acc0 = {0.f, 0.f, 0.f, 0.f};
    float4 acc1 = {0.f, 0.f, 0.f, 0.f};
    int h0[4], h1[4];
#pragma unroll
    for (int j = 0; j < 4; ++j) {
        h0[j] = (4 * lane + j) / 33;
        h1[j] = (4 * (lane + 64) + j) / 33;
    }
    __shared__ float lex[64][8];
    __shared__ int lsrc[64];
    for (int base = 0; base < dg; base += 64) {
        int j = base + lane;
        if (j < dg) {
            int s = csr[r0 + j];
            lsrc[lane] = s;
            const float* ap = as_ + (size_t)s * 8;
#pragma unroll
            for (int h = 0; h < 8; ++h) {
                float e = ap[h] + ad[h];
                e = e > 0.f ? e : NEG * e;
                lex[lane][h] = __expf(e - mx[h]) * inv[h];
            }
        }
        __syncthreads();
        int cnt = min(64, dg - base);
        for (int jj = 0; jj < cnt; ++jj) {
            int s = lsrc[jj];
            const ushort4* row = (const ushort4*)(xb + (size_t)s * LDB);
            ushort4 v = row[lane];
            acc0.x += lex[jj][h0[0]] * bf2f(v.x);
            acc0.y += lex[jj][h0[1]] * bf2f(v.y);
            acc0.z += lex[jj][h0[2]] * bf2f(v.z);
            acc0.w += lex[jj][h0[3]] * bf2f(v.w);
            if (lane < 2) {
                ushort4 w2 = row[64 + lane];
                acc1.x += lex[jj][h1[0]] * bf2f(w2.x);
                acc1.y += lex[jj][h1[1]] * bf2f(w2.y);
                acc1.z += lex[jj][h1[2]] * bf2f(w2.z);
                acc1.w += lex[jj][h1[3]] * bf2f(w2.w);
            }
        }
        __syncthreads();
    }

    // epilogue: bias + elu, split to hi/lo bf16 (next gemm A operand), zero K-pad
#pragma unroll
    for (int k = 0; k < 2; ++k) {
        int i4 = lane + 64 * k;
        if (i4 < 66) {
            float4 a = (k == 0) ? acc0 : acc1;
            float vals[4] = {a.x, a.y, a.z, a.w};
            ushort hi4[4], lo4[4];
#pragma unroll
            for (int j = 0; j < 4; ++j) {
                float v = vals[j] + bias[i4 * 4 + j];
                v = v > 0.f ? v : (__expf(v) - 1.f);
                split2(v, hi4[j], lo4[j]);
            }
            size_t o = (size_t)node * LDA + i4 * 4;
            *(ushort4*)(outhi + o) = *(ushort4*)hi4;
            *(ushort4*)(outlo + o) = *(ushort4*)lo4;
        } else if (i4 < 72) {
            ushort4 z = {0, 0, 0, 0};
            size_t o = (size_t)node * LDA + i4 * 4;
            *(ushort4*)(outhi + o) = z;
            *(ushort4*)(outlo + o) = z;
        }
    }
}

// ---------------- launch ----------------

extern "C" void kernel_launch(void* const* d_in, const int* in_sizes, int n_in,
                              void* d_out, int out_size, void* d_ws, size_t ws_size,
                              hipStream_t stream) {
    const float* x  = (const float*)d_in[0];
    const int*   ei = (const int*)d_in[1];
    const float* W[4]  = {(const float*)d_in[2],  (const float*)d_in[6],
                          (const float*)d_in[10], (const float*)d_in[14]};
    const float* As[4] = {(const float*)d_in[3],  (const float*)d_in[7],
                          (const float*)d_in[11], (const float*)d_in[15]};
    const float* Ad[4] = {(const float*)d_in[4],  (const float*)d_in[8],
                          (const float*)d_in[12], (const float*)d_in[16]};
    const float* Bb[4] = {(const float*)d_in[5],  (const float*)d_in[9],
                          (const float*)d_in[13], (const float*)d_in[17]};
    const float* Wh = (const float*)d_in[18];
    const float* bh = (const float*)d_in[19];

    // ---- workspace carve ----
    char* p = (char*)d_ws;
    float* hB    = (float*)p;           p += (size_t)N_NODES * LDH * 4;      // xh fp32
    ushort* hBb  = (ushort*)p;          p += (size_t)N_NODES * LDB * 2;      // xh bf16 payload
    ushort* hAhi = (ushort*)p;          p += (size_t)N_NODES * LDA * 2;      // A hi
    ushort* hAlo = (ushort*)p;          p += (size_t)N_NODES * LDA * 2;      // A lo
    float* as_  = (float*)p;            p += (size_t)N_NODES * HEADS * 4;
    float* ad_  = (float*)p;            p += (size_t)N_NODES * HEADS * 4;
    const int wsz0 = 4 * NT_HID * 512;
    const int wszH = 9 * NT_HID * 512;
    const int wszO = 9 * NT_HEAD * 512;
    ushort* wfhi[4]; ushort* wflo[4];
    for (int l = 0; l < 4; ++l) {
        int sz = (l == 0) ? wsz0 : wszH;
        wfhi[l] = (ushort*)p; p += (size_t)sz * 2;
        wflo[l] = (ushort*)p; p += (size_t)sz * 2;
    }
    ushort* whhi = (ushort*)p; p += (size_t)wszO * 2;
    ushort* whlo = (ushort*)p; p += (size_t)wszO * 2;
    int* deg  = (int*)p;  p += N_NODES * 4;
    int* cur  = (int*)p;  p += N_NODES * 4;
    int* rowp = (int*)p;  p += (N_NODES + 1) * 4;
    int* csr  = (int*)p;  p += (size_t)TOT_E * 4;

    // ---- CSR build ----
    hipMemsetAsync(deg, 0, sizeof(int) * 2 * N_NODES, stream);  // deg + cur
    int egrid = (TOT_E + 255) / 256;
    deg_k<<<egrid, 256, 0, stream>>>(ei, deg);
    scan_k<<<1, 1024, 0, stream>>>(deg, rowp);
    fill_k<<<egrid, 256, 0, stream>>>(ei, rowp, cur, csr);

    // ---- weight + input conversion ----
    splitx_k<<<(N_NODES * IN_CH + 255) / 256, 256, 0, stream>>>(x, hAhi, hAlo);
    {
        int tot = 4 * NT_HID * 64;
        convw_k<<<(tot + 255) / 256, 256, 0, stream>>>(W[0], IN_CH, DD, NT_HID, wfhi[0], wflo[0], tot);
    }
    for (int l = 1; l < 4; ++l) {
        int tot = 9 * NT_HID * 64;
        convw_k<<<(tot + 255) / 256, 256, 0, stream>>>(W[l], DD, DD, NT_HID, wfhi[l], wflo[l], tot);
    }
    {
        int tot = 9 * NT_HEAD * 64;
        convw_k<<<(tot + 255) / 256, 256, 0, stream>>>(Wh, DD, OUTW, NT_HEAD, whhi, whlo, tot);
    }

    dim3 gG((N_NODES + 63) / 64, 2);   // hidden gemms: 17 tiles = 9 + 8
    dim3 gO((N_NODES + 63) / 64, 1);   // head gemm: 9 tiles
    int agrid = (N_NODES * HEADS + 255) / 256;

    for (int l = 0; l < 4; ++l) {
        int kp = (l == 0) ? 4 : 9;
        gemm_mfma<<<gG, 256, 0, stream>>>(hAhi, hAlo, LDA, kp,
                                          wfhi[l], wflo[l], NT_HID,
                                          hB, LDH, LDH, nullptr, hBb);
        alpha_k<<<agrid, 256, 0, stream>>>(hB, As[l], Ad[l], as_, ad_);
        agg_k<<<N_NODES, 64, 0, stream>>>(hBb, as_, ad_, rowp, csr, Bb[l], hAhi, hAlo);
    }

    // head readout -> fp32 out [N, 132]
    gemm_mfma<<<gO, 256, 0, stream>>>(hAhi, hAlo, LDA, 9,
                                      whhi, whlo, NT_HEAD,
                                      (float*)d_out, OUTW, OUTW, bh, nullptr);
}